// Round 15
// baseline (69.407 us; speedup 1.0000x reference)
//
#include <hip/hip_runtime.h>
#include <cstdint>
#include <cstddef>

#define DEV __device__ __forceinline__

typedef __attribute__((ext_vector_type(8))) short bf16x8;
typedef __attribute__((ext_vector_type(4))) float f32x4;

constexpr int N_  = 16384;
constexpr int D_  = 1024;
constexpr int E_  = 65536;
constexpr int ET_ = E_ + N_;   // edges incl. self loops
constexpr int H_  = 8;
constexpr int C_  = 512;
constexpr int F_  = 4096;      // H_*C_
constexpr int ZS_ = 48;        // Z row: [al_s 0..7|al_d 8..15|z0 16..23|z1 24..31|zd 32..39|pad]
constexpr int NVB = 2048;      // V-build blocks in prep
constexpr int NMB = N_ / 16;   // 1024 mfma blocks (128 thr = 2 K-half waves)

// ---------- helpers ----------
DEV unsigned short f2bf(float f){
  unsigned u = __float_as_uint(f);
  unsigned r = u + 0x7FFFu + ((u >> 16) & 1u); // RNE
  return (unsigned short)(r >> 16);
}
DEV float lrelu(float x){ return x >= 0.f ? x : 0.2f * x; }
DEV float waveSum(float v){
  #pragma unroll
  for (int o = 32; o > 0; o >>= 1) v += __shfl_xor(v, o);
  return v;
}
DEV int eSRC(const int* ei, int e){ return e < E_ ? ei[e]      : e - E_; }
DEV int eDST(const int* ei, int e){ return e < E_ ? ei[E_ + e] : e - E_; }

// ---------- kernel 1: prep = build V (MFMA-B-frag) + cb ----------
// col jj of V: jj=h: W1s_h.a1s[h] | 8+h: W1d_h.a1d[h] | 16+h: W1s_h.W2s[:,0]
//              24+h: W1s_h.W2s[:,1] | 32+h: W1s_h.wd2  (wd2 inline from W2d)
// Vb[((tt*32+kc)*64 + ks*16 + j)*8 + i], tt=jj>>4, j=jj&15, kc=d>>5, ks=(d>>3)&3, i=d&7
__global__ __launch_bounds__(256) void prep(
    const float* __restrict__ W1s, const float* __restrict__ W1d,
    const float* __restrict__ a1s, const float* __restrict__ a1d,
    const float* __restrict__ W2s, const float* __restrict__ W2d,
    const float* __restrict__ a2d, const float* __restrict__ b1,
    unsigned short* __restrict__ Vb, float* __restrict__ cb){
  int t = threadIdx.x;
  int bx = blockIdx.x;
  if (bx < NVB){
    int id = bx * 4 + (t >> 6);            // 0..8191
    int lane = t & 63;
    int d = id >> 3, h = id & 7;
    float a2d0 = a2d[0], a2d1 = a2d[1];
    float sa = 0.f, sb = 0.f, s0 = 0.f, s1 = 0.f, sd = 0.f;
    #pragma unroll
    for (int i = 0; i < C_ / 64; i++){
      int c = i * 64 + lane;
      int gc = h * C_ + c;
      float ws  = W1s[(size_t)d * F_ + gc];
      float wdv = W1d[(size_t)d * F_ + gc];
      sa += ws * a1s[gc]; sb += wdv * a1d[gc];
      float2 w2 = *reinterpret_cast<const float2*>(W2s + (size_t)gc * 2);
      float2 wx = *reinterpret_cast<const float2*>(W2d + (size_t)gc * 2);
      s0 += ws * w2.x; s1 += ws * w2.y;
      sd += ws * (wx.x * a2d0 + wx.y * a2d1);
    }
    sa = waveSum(sa); sb = waveSum(sb);
    s0 = waveSum(s0); s1 = waveSum(s1); sd = waveSum(sd);
    if (lane == 0){
      int kc = d >> 5, ks = (d >> 3) & 3, ii = d & 7;
      auto put = [&](int jj, float v){
        int tt = jj >> 4, j = jj & 15;
        Vb[((size_t)(tt * 32 + kc) * 64 + ks * 16 + j) * 8 + ii] = f2bf(v);
      };
      put(h, sa); put(8 + h, sb); put(16 + h, s0); put(24 + h, s1); put(32 + h, sd);
    }
  } else {
    // cb = (b1.W2s[:,0], b1.W2s[:,1], b1.wd2)
    __shared__ float red[3][4];
    int w = t >> 6, lane = t & 63;
    float a2d0 = a2d[0], a2d1 = a2d[1];
    float p0 = 0.f, p1 = 0.f, pd = 0.f;
    for (int k = t; k < F_; k += 256){
      float b = b1[k];
      float2 w2 = *reinterpret_cast<const float2*>(W2s + (size_t)k * 2);
      float2 wx = *reinterpret_cast<const float2*>(W2d + (size_t)k * 2);
      p0 += b * w2.x; p1 += b * w2.y; pd += b * (wx.x * a2d0 + wx.y * a2d1);
    }
    p0 = waveSum(p0); p1 = waveSum(p1); pd = waveSum(pd);
    if (lane == 0){ red[0][w] = p0; red[1][w] = p1; red[2][w] = pd; }
    __syncthreads();
    if (t == 0){
      cb[0] = red[0][0] + red[0][1] + red[0][2] + red[0][3];
      cb[1] = red[1][0] + red[1][1] + red[1][2] + red[1][3];
      cb[2] = red[2][0] + red[2][1] + red[2][2] + red[2][3];
    }
  }
}

// ---------- kernel 2: Z[n][0..47] = x[n] @ V, in-block K-split x2 + zero region ----------
// 128 threads = 2 waves; wave kh computes K-half, wave1 -> LDS, wave0 sums + stores.
__global__ __launch_bounds__(128) void node_mfma(const float* __restrict__ X,
                                                 const unsigned short* __restrict__ Vb,
                                                 float* __restrict__ Z,
                                                 uint4* __restrict__ zr, int n16){
  int bx = blockIdx.x;
  int t = threadIdx.x;
  if (bx >= NMB){
    // zero the accumulator region (acc/outacc) — consumed only after this
    // kernel's boundary; overlaps the BW-bound mfma blocks
    int i = (bx - NMB) * 128 + t;
    if (i < n16){ uint4 z = {0u,0u,0u,0u}; zr[i] = z; }
    return;
  }
  __shared__ float sm[16][52];               // +4 pad -> 2-way banks (free)
  int kh = t >> 6, lane = t & 63;
  int n0 = bx * 16;
  int row = lane & 15, ks = lane >> 4;
  f32x4 ac0 = {0.f,0.f,0.f,0.f}, ac1 = ac0, ac2 = ac0;
  const float* xp = X + (size_t)(n0 + row) * D_ + ks * 8;
  #pragma unroll 2
  for (int kk = 0; kk < 16; kk++){
    int kc = kh * 16 + kk;
    float4 xa = *reinterpret_cast<const float4*>(xp + kc * 32);
    float4 xb = *reinterpret_cast<const float4*>(xp + kc * 32 + 4);
    bf16x8 a;
    a[0] = (short)f2bf(xa.x); a[1] = (short)f2bf(xa.y);
    a[2] = (short)f2bf(xa.z); a[3] = (short)f2bf(xa.w);
    a[4] = (short)f2bf(xb.x); a[5] = (short)f2bf(xb.y);
    a[6] = (short)f2bf(xb.z); a[7] = (short)f2bf(xb.w);
    bf16x8 b0 = *reinterpret_cast<const bf16x8*>(&Vb[((size_t)( 0 + kc) * 64 + lane) * 8]);
    bf16x8 b1 = *reinterpret_cast<const bf16x8*>(&Vb[((size_t)(32 + kc) * 64 + lane) * 8]);
    bf16x8 b2 = *reinterpret_cast<const bf16x8*>(&Vb[((size_t)(64 + kc) * 64 + lane) * 8]);
    ac0 = __builtin_amdgcn_mfma_f32_16x16x32_bf16(a, b0, ac0, 0, 0, 0);
    ac1 = __builtin_amdgcn_mfma_f32_16x16x32_bf16(a, b1, ac1, 0, 0, 0);
    ac2 = __builtin_amdgcn_mfma_f32_16x16x32_bf16(a, b2, ac2, 0, 0, 0);
  }
  if (kh == 1){
    #pragma unroll
    for (int r = 0; r < 4; r++){
      int nl = ks * 4 + r;
      sm[nl][ 0 + row] = ac0[r];
      sm[nl][16 + row] = ac1[r];
      sm[nl][32 + row] = ac2[r];
    }
  }
  __syncthreads();
  if (kh == 0){
    #pragma unroll
    for (int r = 0; r < 4; r++){
      int nl = ks * 4 + r;
      float* zp = Z + (size_t)(n0 + nl) * ZS_;
      zp[ 0 + row] = ac0[r] + sm[nl][ 0 + row];   // exactly-once plain stores
      zp[16 + row] = ac1[r] + sm[nl][16 + row];
      zp[32 + row] = ac2[r] + sm[nl][32 + row];
    }
  }
}

// ---------- kernel 3: layer-1 fused exp + weighted accumulate ----------
// acc[n][32] = {den 0..7 | a0 8..15 | a1 16..23 | ad 24..31} — 4 atomics in ONE 128B line
__global__ void edge1(const int* __restrict__ ei, const float* __restrict__ Z,
                      float* __restrict__ acc){
  int t = blockIdx.x * blockDim.x + threadIdx.x;
  if (t >= ET_ * H_) return;
  int e = t >> 3, h = t & 7;
  int s = eSRC(ei, e), d = eDST(ei, e);
  const float* zs = Z + (size_t)s * ZS_;
  float ev = expf(lrelu(zs[h] + Z[(size_t)d * ZS_ + 8 + h]));
  float* ap = acc + (size_t)d * 32 + h;
  atomicAdd(ap +  0, ev);
  atomicAdd(ap +  8, ev * zs[16 + h]);
  atomicAdd(ap + 16, ev * zs[24 + h]);
  atomicAdd(ap + 24, ev * zs[32 + h]);
}

// ---------- kernel 4: layer-2 fused (mids recomputed from line-local acc rows) ----------
// outacc[n][4] = {den2, o0, o1, pad} — 3 atomics in ONE 16B segment
__global__ void edge2(const int* __restrict__ ei, const float* __restrict__ acc,
                      const float* __restrict__ cb, const float* __restrict__ a2s,
                      float* __restrict__ outacc){
  int e = blockIdx.x * blockDim.x + threadIdx.x;
  if (e >= ET_) return;
  int s = eSRC(ei, e), d = eDST(ei, e);
  // src row: den (q0,q1), a0 (q2,q3), a1 (q4,q5)  — one 128B line
  const float4* as = reinterpret_cast<const float4*>(acc + (size_t)s * 32);
  float4 q0 = as[0], q1 = as[1], q2 = as[2], q3 = as[3], q4 = as[4], q5 = as[5];
  float i0 = 1.f/(q0.x+1e-16f), i1 = 1.f/(q0.y+1e-16f);
  float i2 = 1.f/(q0.z+1e-16f), i3 = 1.f/(q0.w+1e-16f);
  float i4 = 1.f/(q1.x+1e-16f), i5 = 1.f/(q1.y+1e-16f);
  float i6 = 1.f/(q1.z+1e-16f), i7 = 1.f/(q1.w+1e-16f);
  float v0 = cb[0] + q2.x*i0 + q2.y*i1 + q2.z*i2 + q2.w*i3
                   + q3.x*i4 + q3.y*i5 + q3.z*i6 + q3.w*i7;
  float v1 = cb[1] + q4.x*i0 + q4.y*i1 + q4.z*i2 + q4.w*i3
                   + q5.x*i4 + q5.y*i5 + q5.z*i6 + q5.w*i7;
  // dst row: den (r0,r1), ad (r6,r7) — one 128B line
  const float4* adp = reinterpret_cast<const float4*>(acc + (size_t)d * 32);
  float4 r0 = adp[0], r1 = adp[1], r6 = adp[6], r7 = adp[7];
  float vd = cb[2] + r6.x/(r0.x+1e-16f) + r6.y/(r0.y+1e-16f)
                   + r6.z/(r0.z+1e-16f) + r6.w/(r0.w+1e-16f)
                   + r7.x/(r1.x+1e-16f) + r7.y/(r1.y+1e-16f)
                   + r7.z/(r1.z+1e-16f) + r7.w/(r1.w+1e-16f);
  float als = v0 * a2s[0] + v1 * a2s[1];
  float ev = expf(lrelu(als + vd));
  float* op = outacc + (size_t)d * 4;
  atomicAdd(op + 0, ev);
  atomicAdd(op + 1, ev * v0);
  atomicAdd(op + 2, ev * v1);
}

// ---------- kernel 5: final division + bias -> out ----------
__global__ void node_out(const float4* __restrict__ outacc, const float* __restrict__ b2,
                         float* __restrict__ out){
  int n = blockIdx.x * blockDim.x + threadIdx.x;
  if (n >= N_) return;
  float4 oa = outacc[n];
  float inv = 1.f / (oa.x + 1e-16f);
  out[2 * n]     = oa.y * inv + b2[0];
  out[2 * n + 1] = oa.z * inv + b2[1];
}

// ---------- host ----------
extern "C" void kernel_launch(void* const* d_in, const int* in_sizes, int n_in,
                              void* d_out, int out_size, void* d_ws, size_t ws_size,
                              hipStream_t stream){
  const float* x   = (const float*)d_in[0];
  const int*   ei  = (const int*)  d_in[1];
  const float* W1s = (const float*)d_in[2];
  const float* W1d = (const float*)d_in[3];
  const float* a1s = (const float*)d_in[4];
  const float* a1d = (const float*)d_in[5];
  const float* b1  = (const float*)d_in[6];
  const float* W2s = (const float*)d_in[7];
  const float* W2d = (const float*)d_in[8];
  const float* a2s = (const float*)d_in[9];
  const float* a2d = (const float*)d_in[10];
  const float* b2  = (const float*)d_in[11];
  float* out = (float*)d_out;

  char* p = (char*)d_ws;
  auto alloc = [&](size_t bytes) -> void* {
    void* r = (void*)p;
    p += (bytes + 255) & ~(size_t)255;
    return r;
  };
  float* Z = (float*)alloc((size_t)N_ * ZS_ * 4);    // 3 MB, fully overwritten -> no zeroing
  // ---- contiguous zero region (zeroed inside node_mfma dispatch) ----
  float* acc    = (float*)alloc((size_t)N_ * 32 * 4); // 2 MB interleaved den/a0/a1/ad
  float* outacc = (float*)alloc((size_t)N_ * 16);     // 256 KB interleaved den2/o0/o1
  // ---- end zero region ----
  unsigned short* Vb = (unsigned short*)alloc((size_t)3 * 32 * 64 * 8 * 2); // 96 KB
  float* cb    = (float*)alloc(256);

  size_t zrBytes = (size_t)((char*)Vb - (char*)acc);
  int n16 = (int)(zrBytes / 16);
  int nzb = (n16 + 127) / 128;

  prep<<<dim3(NVB + 1), dim3(256), 0, stream>>>(W1s, W1d, a1s, a1d, W2s, W2d,
                                                a2d, b1, Vb, cb);
  node_mfma<<<dim3(NMB + nzb), dim3(128), 0, stream>>>(x, Vb, Z, (uint4*)acc, n16);
  edge1<<<dim3(ET_ * H_ / 256), dim3(256), 0, stream>>>(ei, Z, acc);
  edge2<<<dim3(ET_ / 256), dim3(256), 0, stream>>>(ei, acc, cb, a2s, outacc);
  node_out<<<dim3(N_ / 256), dim3(256), 0, stream>>>((const float4*)outacc, b2, out);
}

// Round 16
// 67.017 us; speedup vs baseline: 1.0357x; 1.0357x over previous
//
#include <hip/hip_runtime.h>
#include <cstdint>
#include <cstddef>

#define DEV __device__ __forceinline__

typedef __attribute__((ext_vector_type(8))) short bf16x8;
typedef __attribute__((ext_vector_type(4))) float f32x4;

constexpr int N_  = 16384;
constexpr int D_  = 1024;
constexpr int E_  = 65536;
constexpr int ET_ = E_ + N_;   // edges incl. self loops
constexpr int H_  = 8;
constexpr int C_  = 512;
constexpr int F_  = 4096;      // H_*C_
constexpr int KSPLIT = 2;
constexpr int ZS4 = KSPLIT * 48;  // per-node: 2 slices x [al_s 0..7|al_d 8..15|z0|z1|zd|pad]
constexpr int NVB = 2048;      // V-build blocks in prep
constexpr int NMB = (N_ / 16) * KSPLIT;  // 2048 mfma blocks

// ---------- helpers ----------
DEV unsigned short f2bf(float f){
  unsigned u = __float_as_uint(f);
  unsigned r = u + 0x7FFFu + ((u >> 16) & 1u); // RNE
  return (unsigned short)(r >> 16);
}
DEV float lrelu(float x){ return x >= 0.f ? x : 0.2f * x; }
DEV float waveSum(float v){
  #pragma unroll
  for (int o = 32; o > 0; o >>= 1) v += __shfl_xor(v, o);
  return v;
}
DEV int eSRC(const int* ei, int e){ return e < E_ ? ei[e]      : e - E_; }
DEV int eDST(const int* ei, int e){ return e < E_ ? ei[E_ + e] : e - E_; }

// ---------- kernel 1: prep = build V (MFMA-B-frag) + cb ----------
// col jj of V: jj=h: W1s_h.a1s[h] | 8+h: W1d_h.a1d[h] | 16+h: W1s_h.W2s[:,0]
//              24+h: W1s_h.W2s[:,1] | 32+h: W1s_h.wd2  (wd2 inline from W2d)
// Vb[((tt*32+kc)*64 + ks*16 + j)*8 + i], tt=jj>>4, j=jj&15, kc=d>>5, ks=(d>>3)&3, i=d&7
__global__ __launch_bounds__(256) void prep(
    const float* __restrict__ W1s, const float* __restrict__ W1d,
    const float* __restrict__ a1s, const float* __restrict__ a1d,
    const float* __restrict__ W2s, const float* __restrict__ W2d,
    const float* __restrict__ a2d, const float* __restrict__ b1,
    unsigned short* __restrict__ Vb, float* __restrict__ cb){
  int t = threadIdx.x;
  int bx = blockIdx.x;
  if (bx < NVB){
    int id = bx * 4 + (t >> 6);            // 0..8191
    int lane = t & 63;
    int d = id >> 3, h = id & 7;
    float a2d0 = a2d[0], a2d1 = a2d[1];
    float sa = 0.f, sb = 0.f, s0 = 0.f, s1 = 0.f, sd = 0.f;
    #pragma unroll
    for (int i = 0; i < C_ / 64; i++){
      int c = i * 64 + lane;
      int gc = h * C_ + c;
      float ws  = W1s[(size_t)d * F_ + gc];
      float wdv = W1d[(size_t)d * F_ + gc];
      sa += ws * a1s[gc]; sb += wdv * a1d[gc];
      float2 w2 = *reinterpret_cast<const float2*>(W2s + (size_t)gc * 2);
      float2 wx = *reinterpret_cast<const float2*>(W2d + (size_t)gc * 2);
      s0 += ws * w2.x; s1 += ws * w2.y;
      sd += ws * (wx.x * a2d0 + wx.y * a2d1);
    }
    sa = waveSum(sa); sb = waveSum(sb);
    s0 = waveSum(s0); s1 = waveSum(s1); sd = waveSum(sd);
    if (lane == 0){
      int kc = d >> 5, ks = (d >> 3) & 3, ii = d & 7;
      auto put = [&](int jj, float v){
        int tt = jj >> 4, j = jj & 15;
        Vb[((size_t)(tt * 32 + kc) * 64 + ks * 16 + j) * 8 + ii] = f2bf(v);
      };
      put(h, sa); put(8 + h, sb); put(16 + h, s0); put(24 + h, s1); put(32 + h, sd);
    }
  } else {
    // cb = (b1.W2s[:,0], b1.W2s[:,1], b1.wd2)
    __shared__ float red[3][4];
    int w = t >> 6, lane = t & 63;
    float a2d0 = a2d[0], a2d1 = a2d[1];
    float p0 = 0.f, p1 = 0.f, pd = 0.f;
    for (int k = t; k < F_; k += 256){
      float b = b1[k];
      float2 w2 = *reinterpret_cast<const float2*>(W2s + (size_t)k * 2);
      float2 wx = *reinterpret_cast<const float2*>(W2d + (size_t)k * 2);
      p0 += b * w2.x; p1 += b * w2.y; pd += b * (wx.x * a2d0 + wx.y * a2d1);
    }
    p0 = waveSum(p0); p1 = waveSum(p1); pd = waveSum(pd);
    if (lane == 0){ red[0][w] = p0; red[1][w] = p1; red[2][w] = pd; }
    __syncthreads();
    if (t == 0){
      cb[0] = red[0][0] + red[0][1] + red[0][2] + red[0][3];
      cb[1] = red[1][0] + red[1][1] + red[1][2] + red[1][3];
      cb[2] = red[2][0] + red[2][1] + red[2][2] + red[2][3];
    }
  }
}

// ---------- kernel 2: Z4[n][kh][0..47] = x[n] @ V (plain stores) + zero region ----------
__global__ __launch_bounds__(64) void node_mfma(const float* __restrict__ X,
                                                const unsigned short* __restrict__ Vb,
                                                float* __restrict__ Z4,
                                                uint4* __restrict__ zr, int n16){
  int bx = blockIdx.x;
  int lane = threadIdx.x;
  if (bx >= NMB){
    // zero the accumulator region (den1/a0/a1/ad/den2/o0/o1) — consumed only
    // after this kernel's boundary; overlaps the BW-bound mfma blocks
    int i = (bx - NMB) * 64 + lane;
    if (i < n16){ uint4 z = {0u,0u,0u,0u}; zr[i] = z; }
    return;
  }
  int n0 = (bx >> 1) * 16;
  int kh = bx & 1;                           // 0..KSPLIT-1
  int row = lane & 15, ks = lane >> 4;
  f32x4 ac0 = {0.f,0.f,0.f,0.f}, ac1 = ac0, ac2 = ac0;
  const float* xp = X + (size_t)(n0 + row) * D_ + ks * 8;
  constexpr int KC = 32 / KSPLIT;
  #pragma unroll 2
  for (int kk = 0; kk < KC; kk++){
    int kc = kh * KC + kk;
    float4 xa = *reinterpret_cast<const float4*>(xp + kc * 32);
    float4 xb = *reinterpret_cast<const float4*>(xp + kc * 32 + 4);
    bf16x8 a;
    a[0] = (short)f2bf(xa.x); a[1] = (short)f2bf(xa.y);
    a[2] = (short)f2bf(xa.z); a[3] = (short)f2bf(xa.w);
    a[4] = (short)f2bf(xb.x); a[5] = (short)f2bf(xb.y);
    a[6] = (short)f2bf(xb.z); a[7] = (short)f2bf(xb.w);
    bf16x8 b0 = *reinterpret_cast<const bf16x8*>(&Vb[((size_t)( 0 + kc) * 64 + lane) * 8]);
    bf16x8 b1 = *reinterpret_cast<const bf16x8*>(&Vb[((size_t)(32 + kc) * 64 + lane) * 8]);
    bf16x8 b2 = *reinterpret_cast<const bf16x8*>(&Vb[((size_t)(64 + kc) * 64 + lane) * 8]);
    ac0 = __builtin_amdgcn_mfma_f32_16x16x32_bf16(a, b0, ac0, 0, 0, 0);
    ac1 = __builtin_amdgcn_mfma_f32_16x16x32_bf16(a, b1, ac1, 0, 0, 0);
    ac2 = __builtin_amdgcn_mfma_f32_16x16x32_bf16(a, b2, ac2, 0, 0, 0);
  }
  #pragma unroll
  for (int r = 0; r < 4; r++){
    int n = n0 + ks * 4 + r;
    float* zp = Z4 + (size_t)n * ZS4 + kh * 48;
    zp[ 0 + row] = ac0[r];                  // exactly-once plain stores (no atomics)
    zp[16 + row] = ac1[r];
    zp[32 + row] = ac2[r];
  }
}

// ---------- kernel 3: layer-1 fused exp + weighted accumulate (sums 2 slices) ----------
__global__ void edge1(const int* __restrict__ ei, const float* __restrict__ Z4,
                      float* __restrict__ den1, float* __restrict__ a0,
                      float* __restrict__ a1, float* __restrict__ ad){
  int t = blockIdx.x * blockDim.x + threadIdx.x;
  if (t >= ET_ * H_) return;
  int e = t >> 3, h = t & 7;
  int s = eSRC(ei, e), d = eDST(ei, e);
  const float* zs = Z4 + (size_t)s * ZS4;
  const float* zd = Z4 + (size_t)d * ZS4;
  float zsh = 0.f, zdh = 0.f, z0 = 0.f, z1 = 0.f, zdd = 0.f;
  #pragma unroll
  for (int k = 0; k < KSPLIT; k++){
    int o = k * 48;
    zsh += zs[o + h];
    zdh += zd[o + 8 + h];
    z0  += zs[o + 16 + h];
    z1  += zs[o + 24 + h];
    zdd += zs[o + 32 + h];
  }
  float ev = expf(lrelu(zsh + zdh));
  int o = d * 8 + h;
  atomicAdd(&den1[o], ev);
  atomicAdd(&a0[o], ev * z0);
  atomicAdd(&a1[o], ev * z1);
  atomicAdd(&ad[o], ev * zdd);
}

// ---------- kernel 4: per-node head-division + layer-2 logits (packed float4) ----------
// Pn[n] = { als2, v0, v1, vd }
__global__ void node_mid(const float* __restrict__ den1, const float* __restrict__ a0,
                         const float* __restrict__ a1, const float* __restrict__ ad,
                         const float* __restrict__ cb, const float* __restrict__ a2s,
                         float4* __restrict__ Pn){
  int n = blockIdx.x * blockDim.x + threadIdx.x;
  if (n >= N_) return;
  float v0 = 0.f, v1 = 0.f, vd = 0.f;
  #pragma unroll
  for (int h = 0; h < 8; h++){
    float inv = 1.f / (den1[n * 8 + h] + 1e-16f);
    v0 += a0[n * 8 + h] * inv;
    v1 += a1[n * 8 + h] * inv;
    vd += ad[n * 8 + h] * inv;
  }
  v0 += cb[0]; v1 += cb[1]; vd += cb[2];
  float4 r;
  r.x = v0 * a2s[0] + v1 * a2s[1];   // als2
  r.y = v0; r.z = v1;                // layer-2 message values
  r.w = vd;                          // ald2
  Pn[n] = r;
}

// ---------- kernel 5: layer-2 fused exp + weighted accumulate (2 gathers/edge) ----------
__global__ void edge2(const int* __restrict__ ei, const float4* __restrict__ Pn,
                      float* __restrict__ den2, float* __restrict__ o0,
                      float* __restrict__ o1){
  int e = blockIdx.x * blockDim.x + threadIdx.x;
  if (e >= ET_) return;
  int s = eSRC(ei, e), d = eDST(ei, e);
  float4 ps = Pn[s];
  float ald = Pn[d].w;
  float ev = expf(lrelu(ps.x + ald));
  atomicAdd(&den2[d], ev);
  atomicAdd(&o0[d], ev * ps.y);
  atomicAdd(&o1[d], ev * ps.z);
}

// ---------- kernel 6: final division + bias -> out ----------
__global__ void node_out(const float* __restrict__ den2, const float* __restrict__ o0,
                         const float* __restrict__ o1, const float* __restrict__ b2,
                         float* __restrict__ out){
  int n = blockIdx.x * blockDim.x + threadIdx.x;
  if (n >= N_) return;
  float inv = 1.f / (den2[n] + 1e-16f);
  out[2 * n]     = o0[n] * inv + b2[0];
  out[2 * n + 1] = o1[n] * inv + b2[1];
}

// ---------- host ----------
extern "C" void kernel_launch(void* const* d_in, const int* in_sizes, int n_in,
                              void* d_out, int out_size, void* d_ws, size_t ws_size,
                              hipStream_t stream){
  const float* x   = (const float*)d_in[0];
  const int*   ei  = (const int*)  d_in[1];
  const float* W1s = (const float*)d_in[2];
  const float* W1d = (const float*)d_in[3];
  const float* a1s = (const float*)d_in[4];
  const float* a1d = (const float*)d_in[5];
  const float* b1  = (const float*)d_in[6];
  const float* W2s = (const float*)d_in[7];
  const float* W2d = (const float*)d_in[8];
  const float* a2s = (const float*)d_in[9];
  const float* a2d = (const float*)d_in[10];
  const float* b2  = (const float*)d_in[11];
  float* out = (float*)d_out;

  char* p = (char*)d_ws;
  auto alloc = [&](size_t bytes) -> void* {
    void* r = (void*)p;
    p += (bytes + 255) & ~(size_t)255;
    return r;
  };
  float* Z4 = (float*)alloc((size_t)N_ * ZS4 * 4);   // 6 MB, fully overwritten -> no zeroing
  // ---- contiguous zero region (zeroed inside node_mfma dispatch) ----
  float* den1  = (float*)alloc((size_t)N_ * H_ * 4); // 512 KB
  float* a0    = (float*)alloc((size_t)N_ * H_ * 4);
  float* a1    = (float*)alloc((size_t)N_ * H_ * 4);
  float* ad    = (float*)alloc((size_t)N_ * H_ * 4);
  float* den2  = (float*)alloc((size_t)N_ * 4);      // 64 KB
  float* o0    = (float*)alloc((size_t)N_ * 4);
  float* o1    = (float*)alloc((size_t)N_ * 4);
  // ---- end zero region ----
  unsigned short* Vb = (unsigned short*)alloc((size_t)3 * 32 * 64 * 8 * 2); // 96 KB
  float* cb    = (float*)alloc(256);
  float4* Pn   = (float4*)alloc((size_t)N_ * 16);    // 256 KB, fully overwritten

  size_t zrBytes = (size_t)((char*)Vb - (char*)den1);
  int n16 = (int)(zrBytes / 16);
  int nzb = (n16 + 63) / 64;

  prep<<<dim3(NVB + 1), dim3(256), 0, stream>>>(W1s, W1d, a1s, a1d, W2s, W2d,
                                                a2d, b1, Vb, cb);
  node_mfma<<<dim3(NMB + nzb), dim3(64), 0, stream>>>(x, Vb, Z4, (uint4*)den1, n16);
  edge1<<<dim3(ET_ * H_ / 256), dim3(256), 0, stream>>>(ei, Z4, den1, a0, a1, ad);
  node_mid<<<dim3(N_ / 256), dim3(256), 0, stream>>>(den1, a0, a1, ad, cb, a2s, Pn);
  edge2<<<dim3(ET_ / 256), dim3(256), 0, stream>>>(ei, Pn, den2, o0, o1);
  node_out<<<dim3(N_ / 256), dim3(256), 0, stream>>>(den2, o0, o1, b2, out);
}